// Round 1
// baseline (218.654 us; speedup 1.0000x reference)
//
#include <hip/hip_runtime.h>

#define IN_F   4096
#define KSZ    16
#define LOCAL  64
#define FOLDN  4081   // (4096 - 16)/1 + 1
#define BATCH  256

#define F_TILE 16     // folds per block
#define B_SPLIT 4     // blocks along batch
#define B_PER  (BATCH / B_SPLIT)  // 64 batches per block

__global__ __launch_bounds__(256, 4)
void LocalLinear_kernel(const float* __restrict__ x,
                        const float* __restrict__ w,
                        const float* __restrict__ bias,
                        float* __restrict__ out) {
    __shared__ float xs[B_PER][32];   // x[b0+bi][f0 + j], j in [0,32)

    const int t  = threadIdx.x;
    const int f0 = blockIdx.x * F_TILE;
    const int b0 = blockIdx.y * B_PER;

    // ---- stage x tile into LDS (coalesced, guarded at right edge) ----
    for (int idx = t; idx < B_PER * 32; idx += 256) {
        const int bi = idx >> 5;
        const int j  = idx & 31;
        const int col = f0 + j;
        xs[bi][j] = (col < IN_F) ? x[(size_t)(b0 + bi) * IN_F + col] : 0.0f;
    }

    const int l4 = t & 15;    // which float4 of the 64 locals
    const int fi = t >> 4;    // 0..15 within the f tile
    const int f  = f0 + fi;
    const bool valid = (f < FOLDN);

    // ---- weight fragment in registers: w[f][k][4*l4 .. 4*l4+3], k=0..15 ----
    float4 wf[KSZ];
    float4 bv = make_float4(0.f, 0.f, 0.f, 0.f);
    if (valid) {
        const float4* wp = (const float4*)(w + (size_t)f * (KSZ * LOCAL) + l4 * 4);
        #pragma unroll
        for (int k = 0; k < KSZ; ++k)
            wf[k] = wp[(size_t)k * (LOCAL / 4)];   // stride 64 floats
        bv = ((const float4*)(bias + (size_t)f * LOCAL))[l4];
    }

    __syncthreads();

    if (!valid) return;   // no barriers after this point

    float* outp = out + ((size_t)b0 * FOLDN + f) * LOCAL + l4 * 4;
    const size_t ostride = (size_t)FOLDN * LOCAL;

    for (int bi = 0; bi < B_PER; ++bi) {
        float4 acc = bv;
        #pragma unroll
        for (int k = 0; k < KSZ; ++k) {
            const float xv = xs[bi][fi + k];
            acc.x += xv * wf[k].x;
            acc.y += xv * wf[k].y;
            acc.z += xv * wf[k].z;
            acc.w += xv * wf[k].w;
        }
        *(float4*)outp = acc;
        outp += ostride;
    }
}

extern "C" void kernel_launch(void* const* d_in, const int* in_sizes, int n_in,
                              void* d_out, int out_size, void* d_ws, size_t ws_size,
                              hipStream_t stream) {
    const float* x    = (const float*)d_in[0];
    const float* w    = (const float*)d_in[1];
    const float* bias = (const float*)d_in[2];
    float* out = (float*)d_out;

    dim3 grid((FOLDN + F_TILE - 1) / F_TILE, B_SPLIT);  // 256 x 4
    dim3 block(256);
    LocalLinear_kernel<<<grid, block, 0, stream>>>(x, w, bias, out);
}

// Round 3
// 58.735 us; speedup vs baseline: 3.7227x; 3.7227x over previous
//
#include <hip/hip_runtime.h>

#define IN_F   4096
#define KSZ    16
#define LOCAL  64
#define FOLDN  4081   // (4096 - 16)/1 + 1
#define BATCH  256

#define F_TILE 16     // folds per block
#define B_SPLIT 8     // blocks along batch
#define B_PER  (BATCH / B_SPLIT)  // 32 batches per block

typedef float f32x4 __attribute__((ext_vector_type(4)));

__global__ __launch_bounds__(256)
void LocalLinear_kernel(const float* __restrict__ x,
                        const float* __restrict__ w,
                        const float* __restrict__ bias,
                        float* __restrict__ out) {
    __shared__ float xs[B_PER][32];   // x[b0+bi][f0 + j], j in [0,32)

    const int t  = threadIdx.x;
    const int f0 = blockIdx.x * F_TILE;
    const int b0 = blockIdx.y * B_PER;

    // ---- stage x tile into LDS (coalesced, guarded at right edge) ----
    for (int idx = t; idx < B_PER * 32; idx += 256) {
        const int bi = idx >> 5;
        const int j  = idx & 31;
        const int col = f0 + j;
        xs[bi][j] = (col < IN_F) ? x[(size_t)(b0 + bi) * IN_F + col] : 0.0f;
    }

    const int l4 = t & 15;    // which float4 of the 64 locals
    const int fi = t >> 4;    // 0..15 within the f tile
    const int f  = f0 + fi;
    const bool valid = (f < FOLDN);

    // ---- weight fragment in registers: w[f][k][4*l4 .. 4*l4+3], k=0..15 ----
    f32x4 wf[KSZ];
    f32x4 bv = (f32x4)(0.f);
    if (valid) {
        const f32x4* wp = (const f32x4*)(w + (size_t)f * (KSZ * LOCAL) + l4 * 4);
        #pragma unroll
        for (int k = 0; k < KSZ; ++k)
            wf[k] = wp[(size_t)k * (LOCAL / 4)];   // stride 64 floats
        bv = *(const f32x4*)(bias + (size_t)f * LOCAL + l4 * 4);
    }

    __syncthreads();

    if (!valid) return;   // no barriers after this point

    float* outp = out + ((size_t)b0 * FOLDN + f) * LOCAL + l4 * 4;
    const size_t ostride = (size_t)FOLDN * LOCAL;

    for (int bi = 0; bi < B_PER; ++bi) {
        f32x4 acc = bv;
        #pragma unroll
        for (int k = 0; k < KSZ; ++k) {
            const float xv = xs[bi][fi + k];
            acc += xv * wf[k];
        }
        __builtin_nontemporal_store(acc, (f32x4*)outp);  // stream: no L2 RFO
        outp += ostride;
    }
}

extern "C" void kernel_launch(void* const* d_in, const int* in_sizes, int n_in,
                              void* d_out, int out_size, void* d_ws, size_t ws_size,
                              hipStream_t stream) {
    const float* x    = (const float*)d_in[0];
    const float* w    = (const float*)d_in[1];
    const float* bias = (const float*)d_in[2];
    float* out = (float*)d_out;

    dim3 grid((FOLDN + F_TILE - 1) / F_TILE, B_SPLIT);  // 256 x 8
    dim3 block(256);
    LocalLinear_kernel<<<grid, block, 0, stream>>>(x, w, bias, out);
}